// Round 1
// baseline (188.129 us; speedup 1.0000x reference)
//
#include <hip/hip_runtime.h>

#define BTOT 4194304
#define MPW 4   // 64-row macro-groups per wave

typedef __attribute__((ext_vector_type(4))) float f32x4;
typedef __attribute__((ext_vector_type(8))) short bf16x8;

__device__ __forceinline__ short f2bf(float f) {
  union { float f; unsigned u; } v; v.f = f;
  unsigned u = v.u;
  unsigned r = (u + 0x7FFFu + ((u >> 16) & 1u)) >> 16;  // RNE
  return (short)r;
}
__device__ __forceinline__ float bf2f(short s) {
  union { unsigned u; float f; } v; v.u = ((unsigned)(unsigned short)s) << 16;
  return v.f;
}
// tanh(x) = 1 - 2/(1+e^{2x}); e^{2x} = 2^{x*2*log2(e)}. Handles +-inf saturation.
__device__ __forceinline__ float tanh_fast(float x) {
  float t = __builtin_amdgcn_exp2f(x * 2.88539008177792681472f);
  float r = __builtin_amdgcn_rcpf(1.0f + t);
  return __builtin_fmaf(-2.0f, r, 1.0f);
}

__global__ __launch_bounds__(256, 4)
void damping_kernel(const float* __restrict__ x,
                    const float* __restrict__ w_d1, const float* __restrict__ w_d2,
                    const float* __restrict__ w_d3, const float* __restrict__ w_o1,
                    const float* __restrict__ w_o2, const float* __restrict__ w_o3,
                    const float* __restrict__ b_d1, const float* __restrict__ b_d2,
                    const float* __restrict__ b_d3, const float* __restrict__ b_o1,
                    const float* __restrict__ b_o2, const float* __restrict__ b_o3,
                    float* __restrict__ out)
{
  const int tid  = blockIdx.x * blockDim.x + threadIdx.x;
  const int wave = tid >> 6;
  const int l    = threadIdx.x & 63;
  const int g    = l >> 4;      // k-group 0..3
  const int c16  = l & 15;      // row-in-tile (B/A lane dim)
  const int kbase = g * 8;

  // ---- per-lane constants (one-time gathered loads) ----
  // Layer-1 weights: lane computes h1[row=c16][f=kbase+j]; f<16 -> d-net, f>=16 -> o-net
  float W0[8], W1[8], B1[8];
  #pragma unroll
  for (int j = 0; j < 8; ++j) {
    int f = kbase + j;
    if (f < 16) { W0[j] = w_d1[f];      W1[j] = w_d1[16 + f];      B1[j] = b_d1[f]; }
    else        { W0[j] = w_o1[f - 16]; W1[j] = w_o1[16 + f - 16]; B1[j] = b_o1[f - 16]; }
  }
  // A-operand = w2^T (zero-padded per net), split hi/lo bf16 for ~fp32 accuracy
  bf16x8 Adh, Adl, Aoh, Aol;
  #pragma unroll
  for (int j = 0; j < 8; ++j) {
    int k = kbase + j;
    float ad = (k < 16)  ? w_d2[k * 16 + c16]        : 0.0f;
    float ao = (k >= 16) ? w_o2[(k - 16) * 16 + c16] : 0.0f;
    short adh = f2bf(ad); Adh[j] = adh; Adl[j] = f2bf(ad - bf2f(adh));
    short aoh = f2bf(ao); Aoh[j] = aoh; Aol[j] = f2bf(ao - bf2f(aoh));
  }
  // MFMA C-init = layer-2 bias; C[r=(g*4+i)][c16] = d2^T[feat r][row c16]
  f32x4 Cd0, Co0;
  float Wd30[4], Wd31[4], Wo3[4];
  #pragma unroll
  for (int i = 0; i < 4; ++i) {
    int f = g * 4 + i;
    Cd0[i] = b_d2[f]; Co0[i] = b_o2[f];
    Wd30[i] = w_d3[f * 2]; Wd31[i] = w_d3[f * 2 + 1]; Wo3[i] = w_o3[f];
  }
  // layer-3 bias quartered: 4 group-partials sum to full bias
  const float bq0 = b_d3[0] * 0.25f, bq1 = b_d3[1] * 0.25f, bqo = b_o3[0] * 0.25f;

  for (int m = 0; m < MPW; ++m) {
    const int mbase = (wave * MPW + m) * 64;
    float o0 = 0.f, o1 = 0.f;
    #pragma unroll
    for (int t = 0; t < 4; ++t) {
      const int row = mbase + t * 16 + c16;
      const float2 xv = ((const float2*)x)[row];   // 4x redundant across groups; L1 broadcast

      // layer 1 + tanh (8 elems/lane, both nets fused across K=32)
      float h[8];
      #pragma unroll
      for (int j = 0; j < 8; ++j)
        h[j] = tanh_fast(__builtin_fmaf(xv.y, W1[j], __builtin_fmaf(xv.x, W0[j], B1[j])));

      // pack hi/lo bf16 fragments (fed as B operand == d1^T)
      bf16x8 bh, bl;
      #pragma unroll
      for (int j = 0; j < 8; ++j) {
        short hb = f2bf(h[j]); bh[j] = hb;
        bl[j] = f2bf(h[j] - bf2f(hb));
      }

      // layer 2: d2^T = w2^T * d1^T via 3-MFMA hi/lo split per net
      f32x4 accd = Cd0, acco = Co0;
      accd = __builtin_amdgcn_mfma_f32_16x16x32_bf16(Adh, bh, accd, 0, 0, 0);
      acco = __builtin_amdgcn_mfma_f32_16x16x32_bf16(Aoh, bh, acco, 0, 0, 0);
      accd = __builtin_amdgcn_mfma_f32_16x16x32_bf16(Adh, bl, accd, 0, 0, 0);
      acco = __builtin_amdgcn_mfma_f32_16x16x32_bf16(Aoh, bl, acco, 0, 0, 0);
      accd = __builtin_amdgcn_mfma_f32_16x16x32_bf16(Adl, bh, accd, 0, 0, 0);
      acco = __builtin_amdgcn_mfma_f32_16x16x32_bf16(Aol, bh, acco, 0, 0, 0);

      // tanh + layer-3 partials (lane holds feats g*4..g*4+3 of row c16)
      float pd0 = bq0, pd1 = bq1, po = bqo;
      #pragma unroll
      for (int i = 0; i < 4; ++i) {
        float dt = tanh_fast(accd[i]);
        float ot = tanh_fast(acco[i]);
        pd0 = __builtin_fmaf(dt, Wd30[i], pd0);
        pd1 = __builtin_fmaf(dt, Wd31[i], pd1);
        po  = __builtin_fmaf(ot, Wo3[i],  po);
      }
      // reduce across the 4 k-groups
      pd0 += __shfl_xor(pd0, 16); pd0 += __shfl_xor(pd0, 32);
      pd1 += __shfl_xor(pd1, 16); pd1 += __shfl_xor(pd1, 32);
      po  += __shfl_xor(po, 16);  po  += __shfl_xor(po, 32);

      // epilogue (redundant across groups; cheap)
      float a = (fmaxf(pd0, 0.f) + 0.001f) * xv.x;
      float b = (fmaxf(pd1, 0.f) + 0.001f) * xv.y;
      float c = po;
      float D0 = a * __builtin_fmaf(a, xv.x, c * xv.y);
      float s  = __builtin_fmaf(c, c, b * b);
      float D1 = __builtin_fmaf(a * c, xv.x, s * xv.y);

      // lane l owns row mbase+l  <=>  t == g
      if (t == g) { o0 = D0; o1 = D1; }
    }
    ((float2*)out)[mbase + l] = make_float2(o0, o1);  // coalesced 512B/wave
  }
}

extern "C" void kernel_launch(void* const* d_in, const int* in_sizes, int n_in,
                              void* d_out, int out_size, void* d_ws, size_t ws_size,
                              hipStream_t stream) {
  const float* x    = (const float*)d_in[0];
  const float* w_d1 = (const float*)d_in[1];
  const float* w_d2 = (const float*)d_in[2];
  const float* w_d3 = (const float*)d_in[3];
  const float* w_o1 = (const float*)d_in[4];
  const float* w_o2 = (const float*)d_in[5];
  const float* w_o3 = (const float*)d_in[6];
  const float* b_d1 = (const float*)d_in[7];
  const float* b_d2 = (const float*)d_in[8];
  const float* b_d3 = (const float*)d_in[9];
  const float* b_o1 = (const float*)d_in[10];
  const float* b_o2 = (const float*)d_in[11];
  const float* b_o3 = (const float*)d_in[12];
  float* out = (float*)d_out;

  const int waves  = BTOT / (64 * MPW);  // 16384
  const int blocks = waves / 4;          // 4096 blocks of 256 threads
  damping_kernel<<<blocks, 256, 0, stream>>>(x, w_d1, w_d2, w_d3, w_o1, w_o2, w_o3,
                                             b_d1, b_d2, b_d3, b_o1, b_o2, b_o3, out);
}

// Round 3
// 174.423 us; speedup vs baseline: 1.0786x; 1.0786x over previous
//
#include <hip/hip_runtime.h>

#define BTOT 4194304
#define MPW 4   // 64-row macro-groups per wave

typedef __attribute__((ext_vector_type(4))) float f32x4;
typedef __attribute__((ext_vector_type(8))) short bf16x8;

#define KLOG 2.88539008177792681472f  // 2*log2(e)

__device__ __forceinline__ short f2bf(float f) {   // RNE, setup only
  union { float f; unsigned u; } v; v.f = f;
  unsigned u = v.u;
  unsigned r = (u + 0x7FFFu + ((u >> 16) & 1u)) >> 16;
  return (short)r;
}
__device__ __forceinline__ float bf2f(short s) {
  union { unsigned u; float f; } v; v.u = ((unsigned)(unsigned short)s) << 16;
  return v.f;
}
// tanh from PRE-SCALED input y = 2*log2(e)*x:  tanh = 1 - 2/(1+2^y)
__device__ __forceinline__ float tanh_pre(float y) {
  float t = __builtin_amdgcn_exp2f(y);
  float r = __builtin_amdgcn_rcpf(1.0f + t);
  return __builtin_fmaf(-2.0f, r, 1.0f);
}

// Pack 8 floats into hi/lo bf16x8 fragments via truncate-split + v_perm word packing.
// h = hi + lo with |err| <= 2^-16 |h|.
__device__ __forceinline__ void pack_hilo(const float* h, bf16x8& bh, bf16x8& bl) {
  union U { unsigned w[4]; bf16x8 v; } H, L;
  #pragma unroll
  for (int jw = 0; jw < 4; ++jw) {
    float h0 = h[2 * jw], h1 = h[2 * jw + 1];
    unsigned u0 = __builtin_bit_cast(unsigned, h0);
    unsigned u1 = __builtin_bit_cast(unsigned, h1);
    float hi0 = __builtin_bit_cast(float, u0 & 0xFFFF0000u);
    float hi1 = __builtin_bit_cast(float, u1 & 0xFFFF0000u);
    float lo0 = h0 - hi0;                   // exact residual
    float lo1 = h1 - hi1;
    unsigned v0 = __builtin_bit_cast(unsigned, lo0);
    unsigned v1 = __builtin_bit_cast(unsigned, lo1);
    H.w[jw] = __builtin_amdgcn_perm(u1, u0, 0x07060302u);  // [hi16(h1)|hi16(h0)]
    L.w[jw] = __builtin_amdgcn_perm(v1, v0, 0x07060302u);
  }
  bh = H.v; bl = L.v;
}

__global__ __launch_bounds__(256, 4)
void damping_kernel(const float* __restrict__ x,
                    const float* __restrict__ w_d1, const float* __restrict__ w_d2,
                    const float* __restrict__ w_d3, const float* __restrict__ w_o1,
                    const float* __restrict__ w_o2, const float* __restrict__ w_o3,
                    const float* __restrict__ b_d1, const float* __restrict__ b_d2,
                    const float* __restrict__ b_d3, const float* __restrict__ b_o1,
                    const float* __restrict__ b_o2, const float* __restrict__ b_o3,
                    float* __restrict__ out)
{
  const int tid  = blockIdx.x * blockDim.x + threadIdx.x;
  const int wave = tid >> 6;
  const int l    = threadIdx.x & 63;
  const int g    = l >> 4;      // k-group 0..3
  const int c16  = l & 15;      // row-in-tile (B/A lane dim)
  const int kbase = g * 8;

  // ---- per-lane constants (one-time gathered loads) ----
  // Layer-1 weights PRE-SCALED by 2*log2(e) so tanh needs no input mul.
  float W0[8], W1[8], B1[8];
  #pragma unroll
  for (int j = 0; j < 8; ++j) {
    int f = kbase + j;
    if (f < 16) { W0[j] = KLOG * w_d1[f];      W1[j] = KLOG * w_d1[16 + f];      B1[j] = KLOG * b_d1[f]; }
    else        { W0[j] = KLOG * w_o1[f - 16]; W1[j] = KLOG * w_o1[16 + f - 16]; B1[j] = KLOG * b_o1[f - 16]; }
  }
  // A-operand = (2log2e * w2)^T zero-padded per net, RNE hi/lo split (setup-time).
  bf16x8 Adh, Adl, Aoh, Aol;
  #pragma unroll
  for (int j = 0; j < 8; ++j) {
    int k = kbase + j;
    float ad = (k < 16)  ? KLOG * w_d2[k * 16 + c16]        : 0.0f;
    float ao = (k >= 16) ? KLOG * w_o2[(k - 16) * 16 + c16] : 0.0f;
    short adh = f2bf(ad); Adh[j] = adh; Adl[j] = f2bf(ad - bf2f(adh));
    short aoh = f2bf(ao); Aoh[j] = aoh; Aol[j] = f2bf(ao - bf2f(aoh));
  }
  // MFMA C-init = pre-scaled layer-2 bias; C[r=(g*4+i)][c16] = d2^T[feat r][row c16]
  f32x4 Cd0, Co0;
  float Wd30[4], Wd31[4], Wo3[4];
  #pragma unroll
  for (int i = 0; i < 4; ++i) {
    int f = g * 4 + i;
    Cd0[i] = KLOG * b_d2[f]; Co0[i] = KLOG * b_o2[f];
    Wd30[i] = w_d3[f * 2]; Wd31[i] = w_d3[f * 2 + 1]; Wo3[i] = w_o3[f];
  }
  const float bq0 = b_d3[0] * 0.25f, bq1 = b_d3[1] * 0.25f, bqo = b_o3[0] * 0.25f;

  for (int m = 0; m < MPW; ++m) {
    const int mbase = (wave * MPW + m) * 64;

    // preload the 4 x-tiles (VMEM latency hidden under compute)
    float2 xv4[4];
    #pragma unroll
    for (int t = 0; t < 4; ++t)
      xv4[t] = ((const float2*)x)[mbase + t * 16 + c16];

    float o0 = 0.f, o1 = 0.f;
    #pragma unroll
    for (int t = 0; t < 4; ++t) {
      const float2 xv = xv4[t];

      // layer 1 + tanh (8 elems/lane; both nets fused across K=32)
      float h[8];
      #pragma unroll
      for (int j = 0; j < 8; ++j)
        h[j] = tanh_pre(__builtin_fmaf(xv.y, W1[j], __builtin_fmaf(xv.x, W0[j], B1[j])));

      // word-packed hi/lo bf16 fragments (fed as B operand == d1^T)
      bf16x8 bh, bl;
      pack_hilo(h, bh, bl);

      // layer 2: d2^T = w2^T * d1^T via 3-MFMA hi/lo split per net
      f32x4 accd = Cd0, acco = Co0;
      accd = __builtin_amdgcn_mfma_f32_16x16x32_bf16(Adh, bh, accd, 0, 0, 0);
      acco = __builtin_amdgcn_mfma_f32_16x16x32_bf16(Aoh, bh, acco, 0, 0, 0);
      accd = __builtin_amdgcn_mfma_f32_16x16x32_bf16(Adh, bl, accd, 0, 0, 0);
      acco = __builtin_amdgcn_mfma_f32_16x16x32_bf16(Aoh, bl, acco, 0, 0, 0);
      accd = __builtin_amdgcn_mfma_f32_16x16x32_bf16(Adl, bh, accd, 0, 0, 0);
      acco = __builtin_amdgcn_mfma_f32_16x16x32_bf16(Aol, bh, acco, 0, 0, 0);

      // tanh (pre-scaled accums) + layer-3 partials
      float pd0 = bq0, pd1 = bq1, po = bqo;
      #pragma unroll
      for (int i = 0; i < 4; ++i) {
        float dt = tanh_pre(accd[i]);
        float ot = tanh_pre(acco[i]);
        pd0 = __builtin_fmaf(dt, Wd30[i], pd0);
        pd1 = __builtin_fmaf(dt, Wd31[i], pd1);
        po  = __builtin_fmaf(ot, Wo3[i],  po);
      }
      // reduce across the 4 k-groups
      pd0 += __shfl_xor(pd0, 16); pd0 += __shfl_xor(pd0, 32);
      pd1 += __shfl_xor(pd1, 16); pd1 += __shfl_xor(pd1, 32);
      po  += __shfl_xor(po, 16);  po  += __shfl_xor(po, 32);

      // epilogue (redundant across groups; cheap)
      float a = (fmaxf(pd0, 0.f) + 0.001f) * xv.x;
      float b = (fmaxf(pd1, 0.f) + 0.001f) * xv.y;
      float c = po;
      float D0 = a * __builtin_fmaf(a, xv.x, c * xv.y);
      float s  = __builtin_fmaf(c, c, b * b);
      float D1 = __builtin_fmaf(a * c, xv.x, s * xv.y);

      // lane l owns row mbase+l  <=>  t == g
      if (t == g) { o0 = D0; o1 = D1; }
    }
    ((float2*)out)[mbase + l] = make_float2(o0, o1);  // coalesced 512B/wave
  }
}

extern "C" void kernel_launch(void* const* d_in, const int* in_sizes, int n_in,
                              void* d_out, int out_size, void* d_ws, size_t ws_size,
                              hipStream_t stream) {
  const float* x    = (const float*)d_in[0];
  const float* w_d1 = (const float*)d_in[1];
  const float* w_d2 = (const float*)d_in[2];
  const float* w_d3 = (const float*)d_in[3];
  const float* w_o1 = (const float*)d_in[4];
  const float* w_o2 = (const float*)d_in[5];
  const float* w_o3 = (const float*)d_in[6];
  const float* b_d1 = (const float*)d_in[7];
  const float* b_d2 = (const float*)d_in[8];
  const float* b_d3 = (const float*)d_in[9];
  const float* b_o1 = (const float*)d_in[10];
  const float* b_o2 = (const float*)d_in[11];
  const float* b_o3 = (const float*)d_in[12];
  float* out = (float*)d_out;

  const int waves  = BTOT / (64 * MPW);  // 16384
  const int blocks = waves / 4;          // 4096 blocks of 256 threads
  damping_kernel<<<blocks, 256, 0, stream>>>(x, w_d1, w_d2, w_d3, w_o1, w_o2, w_o3,
                                             b_d1, b_d2, b_d3, b_o1, b_o2, b_o3, out);
}